// Round 10
// baseline (211.215 us; speedup 1.0000x reference)
//
#include <hip/hip_runtime.h>
#include <hip/hip_bf16.h>

// GraphSAGEConv: N=50000 nodes, E=800000 edges, D=64 in/out, fp32.
// out = x @ W_self^T + b_self + scatter_mean(x[col] -> row) @ W_neigh^T + b_neigh
//
// R21: single fused kernel with one-way flag-wait (NOT grid.sync: R19 showed
// ROCm's 2-phase barrier costs ~65us; a producer->consumer done-counter poll
// costs only the true dependency latency). Phase 1: 440 statically-assigned
// items (49 x-cast slices + 391 edge chunks, R20 bin code); each item ends
// with __threadfence (L2 writeback) + device-scope done++. Spin: relaxed
// atomic poll + s_sleep, one acquire at exit. Phase 2 = R20 fuse2 with two
// fixes for its +20us mystery: (a) m204 bijective XCD swizzle -> a bucket's
// 4 sibling blocks share one XCD L2 (staging fetched 1x, was 4x = ~12.8MB of
// random HBM lines at the ~20G-line/s wall); (b) phase-A scan 4-deep
// load-batched (was rolled latency-serial).
// Deadlock-safety: all 782 blocks co-resident (LDS 30.7KB -> 5 blk/CU = 1280;
// __launch_bounds__(256,4) caps VGPR<=128 -> >=4 blk/CU = 1024 >= 782).
// Coherence: staged/xb lines never read before the flag; writer wbl2 flushes
// them; gcur read via device-scope atomic. Same machinery as R19's (correct,
// slow) grid.sync.
// Exactness: scnt counts ALL staged edges -> exact mean denominator; staging
// cap 4608 = mean+8sigma (P~0); slots dropped only if deg>64 (P~1e-18).
//
// ws: [xb 6.4MB][staging 196*4608*4=3.61MB][gcur 784B][done 4B] = 10.0MB <= 13MB.
// Pipeline: memset(788B) -> mega_k.

#define D    64
#define CAP  64
#define TPW  16     // nodes per tile (MFMA M)
#define BKN  64     // nodes per block (1/4 of a 256-node staging bucket)
#define SLP  66     // sl row pitch in ushorts (132B: breaks 128B bank alias)
#define EPT  8      // edges per thread per bin chunk (2048/chunk)
#define CHUNK (256 * EPT)
#define CAPB 4608   // staged-edge capacity per bucket (mean 4082 + 8 sigma)
#define CSLICE 16384 // float4 groups per cast item (49 items for N*D/4=800k)

typedef __attribute__((ext_vector_type(8))) short bf16x8;
typedef __attribute__((ext_vector_type(4))) float f32x4;

__device__ __forceinline__ unsigned short f2bf(float f) {   // fp32->bf16 RNE
    unsigned u = __float_as_uint(f);
    return (unsigned short)((u + 0x7fffu + ((u >> 16) & 1u)) >> 16);
}
__device__ __forceinline__ float bf2f(unsigned short s) {
    return __uint_as_float((unsigned)s << 16);
}
__device__ __forceinline__ int load_idx(const void* ei, int use64, long long pos) {
    if (use64) return (int)((const long long*)ei)[pos];
    return ((const int*)ei)[pos];
}

__global__ __launch_bounds__(256, 4) void mega_k(
        const float* __restrict__ x, const void* __restrict__ ei,
        unsigned* __restrict__ staging, unsigned* __restrict__ gcur,
        unsigned* __restrict__ done, unsigned short* __restrict__ xb,
        const float* __restrict__ Ws, const float* __restrict__ bs,
        const float* __restrict__ Wn, const float* __restrict__ bn,
        float* __restrict__ out, int N, int E, int NBr,
        int NV, int NCI, int nitems) {
    __shared__ __align__(16) short wcat[D][136];       // 17.4 KB
    __shared__ __align__(16) short mtile[2][TPW][72];  //  4.6 KB
    __shared__ union {                                  //  8.7 KB
        struct { unsigned lcnt[256]; unsigned lbase[256]; } bin;
        struct { unsigned scnt[BKN]; unsigned short sl[BKN * SLP]; } bkt;
    } u;
    __shared__ int s_use64;
    const int t = threadIdx.x;

    if (t < 64) {   // dtype detect (pure function of ei[0..15])
        long long v = (t < 16) ? ((const long long*)ei)[t] : 0;
        unsigned long long bad = __ballot(t < 16 && (v < 0 || v >= (long long)N));
        if (t == 0) s_use64 = (bad == 0ULL) ? 1 : 0;
    }
    for (int i = t; i < D * 128; i += 256) {   // stage [Ws | Wn] rows, bf16
        int f = i >> 7, kk = i & 127;
        float v = (kk < D) ? Ws[f * D + kk] : Wn[f * D + (kk - D)];
        wcat[f][kk] = (short)f2bf(v);
    }
    __syncthreads();
    const int use64 = s_use64;

    // ---- phase 1: items (cast slices, then bin chunks) ----
    for (int it = blockIdx.x; it < nitems; it += gridDim.x) {
        if (it < NCI) {
            int i0 = it * CSLICE;
            int i1 = i0 + CSLICE; if (i1 > NV) i1 = NV;
            for (int i = i0 + t; i < i1; i += 256) {
                float4 v = *(const float4*)&x[i * 4];
                ushort4 o;
                o.x = f2bf(v.x); o.y = f2bf(v.y);
                o.z = f2bf(v.z); o.w = f2bf(v.w);
                *(ushort4*)&xb[i * 4] = o;
            }
        } else {
            int ch = it - NCI;
            u.bin.lcnt[t] = 0u;
            __syncthreads();
            const int e0 = ch * CHUNK;
            unsigned pk[EPT], lp[EPT];
            int bk[EPT];
            #pragma unroll
            for (int j = 0; j < EPT; ++j) {
                int e = e0 + j * 256 + t;
                if (e < E) {
                    int r = load_idx(ei, use64, e);
                    int c = load_idx(ei, use64, (long long)E + e);
                    pk[j] = ((unsigned)r << 16) | (unsigned)(c & 0xffff);
                    bk[j] = r >> 8;
                    lp[j] = atomicAdd(&u.bin.lcnt[bk[j]], 1u);
                } else bk[j] = -1;
            }
            __syncthreads();
            if (t < NBr) {
                unsigned n = u.bin.lcnt[t];
                u.bin.lbase[t] = n ? atomicAdd(&gcur[t], n) : 0u;
            }
            __syncthreads();
            #pragma unroll
            for (int j = 0; j < EPT; ++j) {
                if (bk[j] >= 0) {
                    unsigned p = u.bin.lbase[bk[j]] + lp[j];
                    if (p < CAPB) staging[(unsigned)bk[j] * CAPB + p] = pk[j];
                }
            }
        }
        __syncthreads();          // all stores of this item drained (vmcnt)
        if (t == 0) {
            __threadfence();      // device-scope release: L2 writeback
            __hip_atomic_fetch_add(done, 1u, __ATOMIC_RELAXED,
                                   __HIP_MEMORY_SCOPE_AGENT);
        }
    }

    // ---- flag-wait: all items done (one-way, not a barrier) ----
    if (t == 0) {
        while (__hip_atomic_load(done, __ATOMIC_RELAXED,
                                 __HIP_MEMORY_SCOPE_AGENT) < (unsigned)nitems)
            __builtin_amdgcn_s_sleep(2);
        (void)__hip_atomic_load(done, __ATOMIC_ACQUIRE,
                                __HIP_MEMORY_SCOPE_AGENT);   // inv stale caches
    }
    __syncthreads();

    // ---- logical window via bijective XCD swizzle (m204): a bucket's 4
    // sibling blocks get consecutive logicals on the SAME XCD -> staging L2-shared
    const int nb  = gridDim.x;
    const int q8  = nb >> 3, r8 = nb & 7;
    const int xcd = blockIdx.x & 7, idx = blockIdx.x >> 3;
    const int logical = (xcd < r8) ? xcd * (q8 + 1) + idx
                                   : r8 * (q8 + 1) + (xcd - r8) * q8 + idx;
    const int node0 = logical * BKN;
    const int qb    = logical >> 2;            // staging bucket

    // ---- phase A: build this block's slot table (4-deep load-batched) ----
    if (t < BKN) u.bkt.scnt[t] = 0u;
    __syncthreads();
    unsigned nstg = __hip_atomic_load(&gcur[qb], __ATOMIC_RELAXED,
                                      __HIP_MEMORY_SCOPE_AGENT);
    if (nstg > CAPB) nstg = CAPB;
    const unsigned* sbase = staging + (size_t)qb * CAPB;
    for (unsigned e = t; e < nstg; e += 1024u) {
        unsigned pks[4]; int have[4];
        #pragma unroll
        for (int k = 0; k < 4; ++k) {
            unsigned ee = e + (unsigned)k * 256u;
            have[k] = (ee < nstg);
            pks[k] = have[k] ? sbase[ee] : 0u;
        }
        #pragma unroll
        for (int k = 0; k < 4; ++k) {
            if (have[k]) {
                int local = (int)(pks[k] >> 16) - node0;
                if ((unsigned)local < (unsigned)BKN) {
                    unsigned pos = atomicAdd(&u.bkt.scnt[local], 1u); // exact deg
                    if (pos < CAP)
                        u.bkt.sl[local * SLP + pos] =
                            (unsigned short)(pks[k] & 0xffffu);
                }
            }
        }
    }
    __syncthreads();

    // ---- phase B: gather + MFMA (R17/R20-proven), 2 iters x 2 tile-pairs ----
    const int w    = t >> 6;
    const int lane = t & 63;
    const int m_   = lane & 15;
    const int quad = lane >> 4;
    const int ql   = m_;
    const int q4   = quad;
    const int pair = w >> 1;
    const int half = w & 1;

    for (int itr = 0; itr < 2; ++itr) {
        const int tile = node0 + (itr * 2 + pair) * TPW;

        #pragma unroll
        for (int pp = 0; pp < 2; ++pp) {
            int p = half * 2 + pp;
            int n = tile + p * 4 + q4;
            int nl = n - node0;                // in [0,64)
            int deg = (n < N) ? (int)u.bkt.scnt[nl] : 0;
            int mm = deg < CAP ? deg : CAP;
            float4 s = make_float4(0.f, 0.f, 0.f, 0.f);
            for (int seg = 0; seg < mm; seg += 16) {
                int sv = (seg + ql < mm) ? (int)u.bkt.sl[nl * SLP + seg + ql] : 0;
                int mq = mm - seg; if (mq > 16) mq = 16;
                unsigned off[16];
                #pragma unroll
                for (int j = 0; j < 16; ++j) {
                    int c = __shfl(sv, (q4 << 4) + j);
                    off[j] = (unsigned)c * D + 4 * ql;
                }
                ushort4 v[16];
                #pragma unroll
                for (int j = 0; j < 16; ++j)
                    v[j] = *(const ushort4*)&xb[off[j]];
                #pragma unroll
                for (int j = 0; j < 16; ++j) {
                    float m = (j < mq) ? 1.0f : 0.0f;
                    s.x = fmaf(m, bf2f(v[j].x), s.x);
                    s.y = fmaf(m, bf2f(v[j].y), s.y);
                    s.z = fmaf(m, bf2f(v[j].z), s.z);
                    s.w = fmaf(m, bf2f(v[j].w), s.w);
                }
            }
            float dinv = (deg > 0) ? 1.0f / (float)deg : 0.0f;
            short4 mv;
            mv.x = (short)f2bf(s.x * dinv); mv.y = (short)f2bf(s.y * dinv);
            mv.z = (short)f2bf(s.z * dinv); mv.w = (short)f2bf(s.w * dinv);
            *(short4*)&mtile[pair][p * 4 + q4][4 * ql] = mv;
        }
        __syncthreads();   // pair's mtile complete before fragment reads

        int nrow = tile + m_;
        const unsigned short* xr = xb + (size_t)(nrow < N ? nrow : 0) * D;
        bf16x8 afrag[4];
        afrag[0] = *(const bf16x8*)&xr[quad * 8];
        afrag[1] = *(const bf16x8*)&xr[32 + quad * 8];
        #pragma unroll
        for (int ks = 2; ks < 4; ++ks)
            afrag[ks] = *(const bf16x8*)&mtile[pair][m_][(ks - 2) * 32 + quad * 8];

        f32x4 acc[2];
        #pragma unroll
        for (int i = 0; i < 2; ++i) {
            int fcol = (half * 2 + i) * 16 + m_;
            float bsum = bs[fcol] + bn[fcol];
            acc[i] = (f32x4){bsum, bsum, bsum, bsum};
        }
        #pragma unroll
        for (int i = 0; i < 2; ++i) {
            int nf = half * 2 + i;
            #pragma unroll
            for (int ks = 0; ks < 4; ++ks) {
                bf16x8 bfr = *(const bf16x8*)&wcat[nf * 16 + m_][ks * 32 + quad * 8];
                acc[i] = __builtin_amdgcn_mfma_f32_16x16x32_bf16(
                    afrag[ks], bfr, acc[i], 0, 0, 0);
            }
        }

        #pragma unroll
        for (int i = 0; i < 2; ++i) {
            int fcol = (half * 2 + i) * 16 + m_;
            #pragma unroll
            for (int r = 0; r < 4; ++r) {
                int node = tile + quad * 4 + r;
                if (node < N) out[(size_t)node * D + fcol] = acc[i][r];
            }
        }
        __syncthreads();   // protect mtile before next iteration's gather
    }
}

// ================= host launcher ============================================
extern "C" void kernel_launch(void* const* d_in, const int* in_sizes, int n_in,
                              void* d_out, int out_size, void* d_ws, size_t ws_size,
                              hipStream_t stream) {
    const float* x  = (const float*)d_in[0];
    const void*  ei = d_in[1];
    const float* Ws = (const float*)d_in[2];
    const float* bs = (const float*)d_in[3];
    const float* Wn = (const float*)d_in[4];
    const float* bn = (const float*)d_in[5];
    float* out = (float*)d_out;

    int N = in_sizes[0] / D;
    int E = in_sizes[1] / 2;

    int NBr = (N + 255) >> 8;                               // 196 buckets
    unsigned short* xb      = (unsigned short*)d_ws;        // 6.4 MB
    unsigned*       staging = (unsigned*)(xb + (size_t)N * D);   // 3.61 MB
    unsigned*       gcur    = staging + (size_t)NBr * CAPB;      // 784 B
    unsigned*       done    = gcur + NBr;                        // 4 B

    hipMemsetAsync(gcur, 0, (size_t)(NBr + 1) * sizeof(unsigned), stream);

    int NV  = (N * D) >> 2;                                 // 800000 float4s
    int NCI = (NV + CSLICE - 1) / CSLICE;                   // 49 cast items
    int nch = (E + CHUNK - 1) / CHUNK;                      // 391 bin chunks
    int nitems  = NCI + nch;                                // 440 items
    int fblocks = (N + BKN - 1) / BKN;                      // 782 blocks

    mega_k<<<fblocks, 256, 0, stream>>>(x, ei, staging, gcur, done, xb,
                                        Ws, bs, Wn, bn, out,
                                        N, E, NBr, NV, NCI, nitems);
}

// Round 12
// 128.892 us; speedup vs baseline: 1.6387x; 1.6387x over previous
//
#include <hip/hip_runtime.h>
#include <hip/hip_bf16.h>

// GraphSAGEConv: N=50000 nodes, E=800000 edges, D=64 in/out, fp32.
// out = x @ W_self^T + b_self + scatter_mean(x[col] -> row) @ W_neigh^T + b_neigh
//
// R23 == R22 resubmitted (R11 bench was an infra failure: container died, no
// measurement). R22: single-kernel fusion abandoned (R18/R19/R21: grid.sync
// 65us, flag-wait ~100us -- device-scope release/acquire on non-coherent
// per-XCD L2s = writeback/invalidate storms; a dispatch boundary ~8us).
// Pipeline = R20's (memset -> bin_k -> fuse2_k) + two fixes:
// (a) m204 bijective XCD swizzle in fuse2_k: the 4 sibling blocks sharing one
// staging bucket get contiguous logicals -> same XCD chunk -> bucket run
// fetched ~1x not 4x (R20's +20us: 12.8MB scattered HBM lines);
// (b) phase-A staged-run scan 4-deep load-batched (was rolled latency-serial).
// Exactness: scnt counts ALL staged edges -> exact mean denominator; staging
// cap 4608 = mean+8sigma (P~0); slots dropped only if deg>64 (P~1e-18).
//
// ws: [xb 6.4MB][staging 196*4608*4=3.61MB][gcur 784B] = 10.0MB <= 13MB.
// d_out untouched until fuse2_k writes it.

#define D    64
#define CAP  64
#define TPW  16     // nodes per tile (MFMA M)
#define BKN  64     // nodes per fuse2 block (1/4 of a 256-node staging bucket)
#define SLP  66     // sl row pitch in ushorts (132B: breaks 128B bank alias)
#define EPT  8      // edges per thread in bin_k (chunk = 2048/block)
#define CAPB 4608   // staged-edge capacity per bucket (mean 4082 + 8 sigma)

typedef __attribute__((ext_vector_type(8))) short bf16x8;
typedef __attribute__((ext_vector_type(4))) float f32x4;

__device__ __forceinline__ unsigned short f2bf(float f) {   // fp32->bf16 RNE
    unsigned u = __float_as_uint(f);
    return (unsigned short)((u + 0x7fffu + ((u >> 16) & 1u)) >> 16);
}
__device__ __forceinline__ float bf2f(unsigned short s) {
    return __uint_as_float((unsigned)s << 16);
}
__device__ __forceinline__ int load_idx(const void* ei, int use64, long long pos) {
    if (use64) return (int)((const long long*)ei)[pos];
    return ((const int*)ei)[pos];
}

// ---- bin: LDS count-sort of edge chunks into per-bucket staged runs --------
// One 2048-edge chunk per block. Per edge: 1 LDS atomic; one global atomic per
// nonempty (block,bucket); contiguous 4B run-writes. Dtype detect inlined.
// xb cast rides in the streaming tail (R11-proven free rider).
__global__ __launch_bounds__(256) void bin_k(
        const float* __restrict__ x, const void* __restrict__ ei,
        unsigned* __restrict__ staging, unsigned* __restrict__ gcur,
        unsigned short* __restrict__ xb, int N, int E, int NBr) {
    __shared__ unsigned lcnt[256];
    __shared__ unsigned lbase[256];
    __shared__ int s_use64;
    const int t = threadIdx.x;
    lcnt[t] = 0u;
    if (t < 64) {   // wave 0: dtype detect (pure function of ei[0..15])
        long long v = (t < 16) ? ((const long long*)ei)[t] : 0;
        unsigned long long bad = __ballot(t < 16 && (v < 0 || v >= (long long)N));
        if (t == 0) s_use64 = (bad == 0ULL) ? 1 : 0;
    }
    __syncthreads();
    const int use64 = s_use64;
    const int e0 = blockIdx.x * (256 * EPT);
    unsigned pk[EPT], lp[EPT];
    int bk[EPT];
    #pragma unroll
    for (int j = 0; j < EPT; ++j) {
        int e = e0 + j * 256 + t;
        if (e < E) {
            int r = load_idx(ei, use64, e);
            int c = load_idx(ei, use64, (long long)E + e);
            pk[j] = ((unsigned)r << 16) | (unsigned)(c & 0xffff);
            bk[j] = r >> 8;
            lp[j] = atomicAdd(&lcnt[bk[j]], 1u);
        } else bk[j] = -1;
    }
    __syncthreads();
    if (t < NBr) {
        unsigned n = lcnt[t];
        lbase[t] = n ? atomicAdd(&gcur[t], n) : 0u;
    }
    __syncthreads();
    #pragma unroll
    for (int j = 0; j < EPT; ++j) {
        if (bk[j] >= 0) {
            unsigned p = lbase[bk[j]] + lp[j];
            if (p < CAPB) staging[(unsigned)bk[j] * CAPB + p] = pk[j];
        }
    }
    // ---- streaming rider: x -> bf16 cast ----
    int tid = blockIdx.x * 256 + t;
    int NT  = gridDim.x * 256;
    int NV  = (N * D) >> 2;                    // float4 groups
    for (int i = tid; i < NV; i += NT) {
        float4 v = *(const float4*)&x[i * 4];
        ushort4 o;
        o.x = f2bf(v.x); o.y = f2bf(v.y); o.z = f2bf(v.z); o.w = f2bf(v.w);
        *(ushort4*)&xb[i * 4] = o;
    }
}

// ---- fuse2: in-LDS bucket build + gather-mean + MFMA dual linear -----------
// m204 bijective XCD swizzle: logical block id laid out in contiguous
// per-XCD chunks (xcd = blockIdx%8 heuristic, m09); the 4 siblings sharing
// staging bucket (logical>>2) get consecutive logicals -> same XCD -> the
// bucket's ~16KB run is L2-shared, fetched once.
// Phase A: scan bucket run 4-deep batched, filter into 64-node window, build
// scnt[64]+sl[64][66] via LDS atomics. Phase B: R17/R20-proven gather+MFMA.
// Layouts (R9/R10-proven): A[m=lane&15][k=quad*8+j], B[k][n=lane&15],
// C/D col=lane&15 row=quad*4+reg.
__global__ __launch_bounds__(256) void fuse2_k(
        const unsigned short* __restrict__ xb,
        const unsigned* __restrict__ staging, const unsigned* __restrict__ gcur,
        const float* __restrict__ Ws, const float* __restrict__ bs,
        const float* __restrict__ Wn, const float* __restrict__ bn,
        float* __restrict__ out, int N) {
    __shared__ __align__(16) short wcat[D][136];       // 17.4 KB
    __shared__ __align__(16) short mtile[2][TPW][72];  //  4.6 KB
    __shared__ unsigned short sl[BKN * SLP];           //  8.4 KB
    __shared__ unsigned scnt[BKN];

    const int t = threadIdx.x;

    // ---- m204 bijective swizzle over gridDim blocks ----
    const int nb  = gridDim.x;
    const int q8  = nb >> 3, r8 = nb & 7;
    const int xcd = blockIdx.x & 7, idx = blockIdx.x >> 3;
    const int logical = (xcd < r8) ? xcd * (q8 + 1) + idx
                                   : r8 * (q8 + 1) + (xcd - r8) * q8 + idx;
    const int node0 = logical * BKN;
    const int qb    = logical >> 2;            // staging bucket

    for (int i = t; i < D * 128; i += 256) {   // stage [Ws | Wn] rows, bf16
        int f = i >> 7, kk = i & 127;
        float v = (kk < D) ? Ws[f * D + kk] : Wn[f * D + (kk - D)];
        wcat[f][kk] = (short)f2bf(v);
    }
    if (t < BKN) scnt[t] = 0u;
    __syncthreads();

    // ---- phase A: build this block's slot table (4-deep load-batched) ----
    unsigned nstg = gcur[qb]; if (nstg > CAPB) nstg = CAPB;
    const unsigned* sbase = staging + (size_t)qb * CAPB;
    for (unsigned e = t; e < nstg; e += 1024u) {
        unsigned pks[4]; int have[4];
        #pragma unroll
        for (int k = 0; k < 4; ++k) {
            unsigned ee = e + (unsigned)k * 256u;
            have[k] = (ee < nstg);
            pks[k] = have[k] ? sbase[ee] : 0u;
        }
        #pragma unroll
        for (int k = 0; k < 4; ++k) {
            if (have[k]) {
                int local = (int)(pks[k] >> 16) - node0;
                if ((unsigned)local < (unsigned)BKN) {
                    unsigned pos = atomicAdd(&scnt[local], 1u);   // exact degree
                    if (pos < CAP)
                        sl[local * SLP + pos] = (unsigned short)(pks[k] & 0xffffu);
                }
            }
        }
    }
    __syncthreads();

    // ---- phase B: gather + MFMA, 2 iterations x 2 tile-pairs ----
    const int w    = t >> 6;
    const int lane = t & 63;
    const int m_   = lane & 15;
    const int quad = lane >> 4;
    const int ql   = m_;
    const int q4   = quad;
    const int pair = w >> 1;
    const int half = w & 1;

    for (int it = 0; it < 2; ++it) {
        const int tile = node0 + (it * 2 + pair) * TPW;

        #pragma unroll
        for (int pp = 0; pp < 2; ++pp) {
            int p = half * 2 + pp;
            int n = tile + p * 4 + q4;
            int nl = n - node0;                // in [0,64)
            int deg = (n < N) ? (int)scnt[nl] : 0;
            int mm = deg < CAP ? deg : CAP;
            float4 s = make_float4(0.f, 0.f, 0.f, 0.f);
            for (int seg = 0; seg < mm; seg += 16) {
                int sv = (seg + ql < mm) ? (int)sl[nl * SLP + seg + ql] : 0;
                int mq = mm - seg; if (mq > 16) mq = 16;
                unsigned off[16];
                #pragma unroll
                for (int j = 0; j < 16; ++j) {
                    int c = __shfl(sv, (q4 << 4) + j);
                    off[j] = (unsigned)c * D + 4 * ql;
                }
                ushort4 v[16];
                #pragma unroll
                for (int j = 0; j < 16; ++j)
                    v[j] = *(const ushort4*)&xb[off[j]];
                #pragma unroll
                for (int j = 0; j < 16; ++j) {
                    float m = (j < mq) ? 1.0f : 0.0f;
                    s.x = fmaf(m, bf2f(v[j].x), s.x);
                    s.y = fmaf(m, bf2f(v[j].y), s.y);
                    s.z = fmaf(m, bf2f(v[j].z), s.z);
                    s.w = fmaf(m, bf2f(v[j].w), s.w);
                }
            }
            float dinv = (deg > 0) ? 1.0f / (float)deg : 0.0f;
            short4 mv;
            mv.x = (short)f2bf(s.x * dinv); mv.y = (short)f2bf(s.y * dinv);
            mv.z = (short)f2bf(s.z * dinv); mv.w = (short)f2bf(s.w * dinv);
            *(short4*)&mtile[pair][p * 4 + q4][4 * ql] = mv;
        }
        __syncthreads();   // pair's mtile complete before fragment reads

        int nrow = tile + m_;
        const unsigned short* xr = xb + (size_t)(nrow < N ? nrow : 0) * D;
        bf16x8 afrag[4];
        afrag[0] = *(const bf16x8*)&xr[quad * 8];
        afrag[1] = *(const bf16x8*)&xr[32 + quad * 8];
        #pragma unroll
        for (int ks = 2; ks < 4; ++ks)
            afrag[ks] = *(const bf16x8*)&mtile[pair][m_][(ks - 2) * 32 + quad * 8];

        f32x4 acc[2];
        #pragma unroll
        for (int i = 0; i < 2; ++i) {
            int fcol = (half * 2 + i) * 16 + m_;
            float bsum = bs[fcol] + bn[fcol];
            acc[i] = (f32x4){bsum, bsum, bsum, bsum};
        }
        #pragma unroll
        for (int i = 0; i < 2; ++i) {
            int nf = half * 2 + i;
            #pragma unroll
            for (int ks = 0; ks < 4; ++ks) {
                bf16x8 bfr = *(const bf16x8*)&wcat[nf * 16 + m_][ks * 32 + quad * 8];
                acc[i] = __builtin_amdgcn_mfma_f32_16x16x32_bf16(
                    afrag[ks], bfr, acc[i], 0, 0, 0);
            }
        }

        #pragma unroll
        for (int i = 0; i < 2; ++i) {
            int fcol = (half * 2 + i) * 16 + m_;
            #pragma unroll
            for (int r = 0; r < 4; ++r) {
                int node = tile + quad * 4 + r;
                if (node < N) out[(size_t)node * D + fcol] = acc[i][r];
            }
        }
        __syncthreads();   // protect mtile before next iteration's gather
    }
}

// ================= host launcher ============================================
extern "C" void kernel_launch(void* const* d_in, const int* in_sizes, int n_in,
                              void* d_out, int out_size, void* d_ws, size_t ws_size,
                              hipStream_t stream) {
    const float* x  = (const float*)d_in[0];
    const void*  ei = d_in[1];
    const float* Ws = (const float*)d_in[2];
    const float* bs = (const float*)d_in[3];
    const float* Wn = (const float*)d_in[4];
    const float* bn = (const float*)d_in[5];
    float* out = (float*)d_out;

    int N = in_sizes[0] / D;
    int E = in_sizes[1] / 2;

    int NBr = (N + 255) >> 8;                               // 196 buckets
    unsigned short* xb      = (unsigned short*)d_ws;        // 6.4 MB
    unsigned*       staging = (unsigned*)(xb + (size_t)N * D);   // 3.61 MB
    unsigned*       gcur    = staging + (size_t)NBr * CAPB;      // 784 B

    hipMemsetAsync(gcur, 0, (size_t)NBr * sizeof(unsigned), stream);

    int binb = (E + 256 * EPT - 1) / (256 * EPT);           // 391 blocks
    bin_k<<<binb, 256, 0, stream>>>(x, ei, staging, gcur, xb, N, E, NBr);

    int fblocks = (N + BKN - 1) / BKN;                      // 782 blocks
    fuse2_k<<<fblocks, 256, 0, stream>>>(xb, staging, gcur,
                                         Ws, bs, Wn, bn, out, N);
}

// Round 13
// 128.802 us; speedup vs baseline: 1.6398x; 1.0007x over previous
//
#include <hip/hip_runtime.h>
#include <hip/hip_bf16.h>

// GraphSAGEConv: N=50000 nodes, E=800000 edges, D=64 in/out, fp32.
// out = x @ W_self^T + b_self + scatter_mean(x[col] -> row) @ W_neigh^T + b_neigh
//
// R24: cursorless fixed-cell staging + BKN=128 fuse.
// Evidence trail: R16 (4 dispatches) 125.1; R23 (3 dispatches, fuse2 BKN=64)
// 128.9 -> fuse2's 4x bucket-filter amplification (~12us) ate the boundary
// saving; memset+boundary ~10us; bin's 77k global cursor atomics ~4us.
// This round:
//  - staging: one cell per (bucket, chunk-pair), CELLCAP=160 u32. The two bin
//    blocks of a chunk-pair write the SAME cell from OPPOSITE ends (asc/desc)
//    -> disjoint without atomics. Per-cell counts written fresh each iter ->
//    poisoned tails never read -> NO memset, NO gcur. Overflow iff >160 of
//    16384 edges hit one bucket: Chernoff P<=6e-13/cell x 9.6k cells ~ 6e-9.
//  - bin_k: 98 bin blocks (8192 edges each) + 196 cast blocks in ONE dispatch
//    (cast no longer a serial rider).
//  - fuse3_k: BKN=128, 512 thr -> filter amplification 2x (was 4x); phase A
//    flat-scans the bucket's 49 cells (31.4KB) with validity from counts;
//    m204 bijective XCD swizzle keeps the 2 sibling blocks of a bucket on one
//    XCD (L2-shared scan). Phase B = R17/R23-proven gather+MFMA.
// Pipeline: bin_k -> fuse3_k (2 dispatches, 1 boundary, 0 global atomics).
// Exactness: degree = count of scanned valid entries = all staged edges
// (exact unless cell overflow, P~6e-9); per-node slots dropped only if
// deg>64 (Poisson(16): P~1e-18).
//
// ws: [xb 6,400,000][staging 196*49*160*4=6,146,560][lcnt_g 2*196*49*4=76,832]
//     = 12,623,392 B <= 13.0 MB budget.

#define D       64
#define CAP     64      // per-node slot cap in LDS
#define TPW     16      // nodes per MFMA tile
#define BKN     128     // nodes per fuse3 block (half a 256-node bucket)
#define SLP     66      // sl row pitch in ushorts (132B: breaks 128B alias)
#define CPE     16384   // edges per chunk-pair
#define HALFE   8192    // edges per bin block (half chunk-pair)
#define CELLCAP 160     // u32 entries per (bucket, chunk-pair) cell

typedef __attribute__((ext_vector_type(8))) short bf16x8;
typedef __attribute__((ext_vector_type(4))) float f32x4;

__device__ __forceinline__ unsigned short f2bf(float f) {   // fp32->bf16 RNE
    unsigned u = __float_as_uint(f);
    return (unsigned short)((u + 0x7fffu + ((u >> 16) & 1u)) >> 16);
}
__device__ __forceinline__ float bf2f(unsigned short s) {
    return __uint_as_float((unsigned)s << 16);
}
__device__ __forceinline__ int load_idx(const void* ei, int use64, long long pos) {
    if (use64) return (int)((const long long*)ei)[pos];
    return ((const int*)ei)[pos];
}

// ---- bin: cursorless fixed-cell count-sort + concurrent x->bf16 cast -------
// Block b < nbin: bin block. cp = b>>1, dir = b&1. Handles edges
// [cp*CPE + dir*HALFE, min(E, ..+HALFE)). Writes cell (bk, cp) ascending
// (dir=0) or descending (dir=1); count -> lcnt_g[dir][bk][cp]. No atomics.
// Block b >= nbin: cast block (grid-stride over x).
__global__ __launch_bounds__(256) void bin_k(
        const float* __restrict__ x, const void* __restrict__ ei,
        unsigned* __restrict__ staging, unsigned* __restrict__ lcnt_g,
        unsigned short* __restrict__ xb,
        int N, int E, int NBuk, int NCH, int nbin) {
    const int t = threadIdx.x;
    if ((int)blockIdx.x >= nbin) {
        // ---- cast block ----
        int cb  = blockIdx.x - nbin;
        int ncb = gridDim.x - nbin;
        int NV  = (N * D) >> 2;                    // float4 groups
        for (int i = cb * 256 + t; i < NV; i += ncb * 256) {
            float4 v = *(const float4*)&x[i * 4];
            ushort4 o;
            o.x = f2bf(v.x); o.y = f2bf(v.y); o.z = f2bf(v.z); o.w = f2bf(v.w);
            *(ushort4*)&xb[i * 4] = o;
        }
        return;
    }
    // ---- bin block ----
    __shared__ unsigned lcnt[256];
    __shared__ int s_use64;
    lcnt[t] = 0u;
    if (t < 64) {   // dtype detect (pure function of ei[0..15])
        long long v = (t < 16) ? ((const long long*)ei)[t] : 0;
        unsigned long long bad = __ballot(t < 16 && (v < 0 || v >= (long long)N));
        if (t == 0) s_use64 = (bad == 0ULL) ? 1 : 0;
    }
    __syncthreads();
    const int use64 = s_use64;
    const int cp  = blockIdx.x >> 1;
    const int dir = blockIdx.x & 1;
    const int e0 = cp * CPE + dir * HALFE;
    int e1 = e0 + HALFE; if (e1 > E) e1 = E;

    for (int sb = 0; sb < 4; ++sb) {           // 4 sub-batches of 8 edges/thr
        unsigned pk[8], lp[8];
        int bk[8];
        #pragma unroll
        for (int j = 0; j < 8; ++j) {
            int e = e0 + sb * 2048 + j * 256 + t;
            if (e < e1) {
                int r = load_idx(ei, use64, e);
                int c = load_idx(ei, use64, (long long)E + e);
                pk[j] = ((unsigned)r << 16) | (unsigned)(c & 0xffff);
                bk[j] = r >> 8;
                lp[j] = atomicAdd(&lcnt[bk[j]], 1u);    // LDS only
            } else bk[j] = -1;
        }
        #pragma unroll
        for (int j = 0; j < 8; ++j) {
            if (bk[j] >= 0 && lp[j] < CELLCAP) {
                unsigned pos = dir ? (CELLCAP - 1u - lp[j]) : lp[j];
                staging[((unsigned)bk[j] * NCH + cp) * CELLCAP + pos] = pk[j];
            }
        }
    }
    __syncthreads();
    if (t < NBuk)
        lcnt_g[(size_t)dir * NBuk * NCH + (size_t)t * NCH + cp] = lcnt[t];
}

// ---- fuse3: in-LDS half-bucket build + gather-mean + MFMA dual linear ------
// 512 threads; block owns 128 nodes (half of bucket q = logical>>1).
// m204 bijective XCD swizzle -> the 2 sibling blocks of a bucket share an XCD
// (cell range L2-shared). Phase A: flat-scan the bucket's NCH cells; entry at
// flat idx is valid iff pos < cntA[cell] or pos >= CELLCAP-cntB[cell]
// (counts fresh-written by bin_k; poisoned tails skipped by position).
// Phase B: proven gather+MFMA: 4 wave-pairs x 2 iters over 8 tiles.
// Layouts (R9/R10-proven): A[m=lane&15][k=quad*8+j], B[k][n=lane&15],
// C/D col=lane&15 row=quad*4+reg.
__global__ __launch_bounds__(512) void fuse3_k(
        const unsigned short* __restrict__ xb,
        const unsigned* __restrict__ staging, const unsigned* __restrict__ lcnt_g,
        const float* __restrict__ Ws, const float* __restrict__ bs,
        const float* __restrict__ Wn, const float* __restrict__ bn,
        float* __restrict__ out, int N, int NBuk, int NCH) {
    __shared__ __align__(16) short wcat[D][136];       // 17.4 KB
    __shared__ __align__(16) short mtile[4][TPW][72];  //  9.2 KB
    __shared__ unsigned short sl[BKN * SLP];           // 16.9 KB
    __shared__ unsigned scnt[BKN];
    __shared__ unsigned short cA[64], cB[64];          // NCH<=64 cell counts

    const int t = threadIdx.x;

    // ---- m204 bijective swizzle over gridDim blocks ----
    const int nb  = gridDim.x;
    const int q8  = nb >> 3, r8 = nb & 7;
    const int xcd = blockIdx.x & 7, idx = blockIdx.x >> 3;
    const int logical = (xcd < r8) ? xcd * (q8 + 1) + idx
                                   : r8 * (q8 + 1) + (xcd - r8) * q8 + idx;
    const int node0 = logical * BKN;
    const int q     = logical >> 1;            // bucket

    for (int i = t; i < D * 128; i += 512) {   // stage [Ws | Wn] rows, bf16
        int f = i >> 7, kk = i & 127;
        float v = (kk < D) ? Ws[f * D + kk] : Wn[f * D + (kk - D)];
        wcat[f][kk] = (short)f2bf(v);
    }
    if (t < BKN) scnt[t] = 0u;
    if (t < NCH) {
        unsigned a = lcnt_g[(size_t)q * NCH + t];
        if (a > CELLCAP) a = CELLCAP;
        unsigned b = lcnt_g[(size_t)NBuk * NCH + (size_t)q * NCH + t];
        if (b > CELLCAP - a) b = CELLCAP - a;
        cA[t] = (unsigned short)a; cB[t] = (unsigned short)b;
    }
    __syncthreads();

    // ---- phase A: flat-scan bucket cells, filter into 128-node window ----
    const unsigned* sbase = staging + (size_t)q * NCH * CELLCAP;
    const int ncell = NCH * CELLCAP;           // 7840 entries
    for (int b0 = 0; b0 < ncell; b0 += 2048) {
        unsigned pks[4]; int iv[4];
        #pragma unroll
        for (int k = 0; k < 4; ++k) {
            int ix = b0 + k * 512 + t;
            iv[k] = (ix < ncell) ? ix : -1;
            pks[k] = (iv[k] >= 0) ? sbase[ix] : 0u;
        }
        #pragma unroll
        for (int k = 0; k < 4; ++k) {
            if (iv[k] >= 0) {
                int cell = iv[k] / CELLCAP, pos = iv[k] - cell * CELLCAP;
                if (pos < (int)cA[cell] || pos >= CELLCAP - (int)cB[cell]) {
                    int local = (int)(pks[k] >> 16) - node0;
                    if ((unsigned)local < (unsigned)BKN) {
                        unsigned p = atomicAdd(&scnt[local], 1u);  // exact deg
                        if (p < CAP)
                            sl[local * SLP + p] =
                                (unsigned short)(pks[k] & 0xffffu);
                    }
                }
            }
        }
    }
    __syncthreads();

    // ---- phase B: gather + MFMA, 4 wave-pairs x 2 iterations (8 tiles) ----
    const int w    = t >> 6;
    const int lane = t & 63;
    const int m_   = lane & 15;
    const int quad = lane >> 4;
    const int ql   = m_;
    const int q4   = quad;
    const int pair = w >> 1;                   // [0,4)
    const int half = w & 1;

    for (int it = 0; it < 2; ++it) {
        const int tile = node0 + (it * 4 + pair) * TPW;

        #pragma unroll
        for (int pp = 0; pp < 2; ++pp) {
            int p = half * 2 + pp;
            int n = tile + p * 4 + q4;
            int nl = n - node0;                // in [0,128)
            int deg = (n < N) ? (int)scnt[nl] : 0;
            int mm = deg < CAP ? deg : CAP;
            float4 s = make_float4(0.f, 0.f, 0.f, 0.f);
            for (int seg = 0; seg < mm; seg += 16) {
                int sv = (seg + ql < mm) ? (int)sl[nl * SLP + seg + ql] : 0;
                int mq = mm - seg; if (mq > 16) mq = 16;
                unsigned off[16];
                #pragma unroll
                for (int j = 0; j < 16; ++j) {
                    int c = __shfl(sv, (q4 << 4) + j);
                    off[j] = (unsigned)c * D + 4 * ql;
                }
                ushort4 v[16];
                #pragma unroll
                for (int j = 0; j < 16; ++j)
                    v[j] = *(const ushort4*)&xb[off[j]];
                #pragma unroll
                for (int j = 0; j < 16; ++j) {
                    float m = (j < mq) ? 1.0f : 0.0f;
                    s.x = fmaf(m, bf2f(v[j].x), s.x);
                    s.y = fmaf(m, bf2f(v[j].y), s.y);
                    s.z = fmaf(m, bf2f(v[j].z), s.z);
                    s.w = fmaf(m, bf2f(v[j].w), s.w);
                }
            }
            float dinv = (deg > 0) ? 1.0f / (float)deg : 0.0f;
            short4 mv;
            mv.x = (short)f2bf(s.x * dinv); mv.y = (short)f2bf(s.y * dinv);
            mv.z = (short)f2bf(s.z * dinv); mv.w = (short)f2bf(s.w * dinv);
            *(short4*)&mtile[pair][p * 4 + q4][4 * ql] = mv;
        }
        __syncthreads();   // pair's mtile complete before fragment reads

        int nrow = tile + m_;
        const unsigned short* xr = xb + (size_t)(nrow < N ? nrow : 0) * D;
        bf16x8 afrag[4];
        afrag[0] = *(const bf16x8*)&xr[quad * 8];
        afrag[1] = *(const bf16x8*)&xr[32 + quad * 8];
        #pragma unroll
        for (int ks = 2; ks < 4; ++ks)
            afrag[ks] = *(const bf16x8*)&mtile[pair][m_][(ks - 2) * 32 + quad * 8];

        f32x4 acc[2];
        #pragma unroll
        for (int i = 0; i < 2; ++i) {
            int fcol = (half * 2 + i) * 16 + m_;
            float bsum = bs[fcol] + bn[fcol];
            acc[i] = (f32x4){bsum, bsum, bsum, bsum};
        }
        #pragma unroll
        for (int i = 0; i < 2; ++i) {
            int nf = half * 2 + i;
            #pragma unroll
            for (int ks = 0; ks < 4; ++ks) {
                bf16x8 bfr = *(const bf16x8*)&wcat[nf * 16 + m_][ks * 32 + quad * 8];
                acc[i] = __builtin_amdgcn_mfma_f32_16x16x32_bf16(
                    afrag[ks], bfr, acc[i], 0, 0, 0);
            }
        }

        #pragma unroll
        for (int i = 0; i < 2; ++i) {
            int fcol = (half * 2 + i) * 16 + m_;
            #pragma unroll
            for (int r = 0; r < 4; ++r) {
                int node = tile + quad * 4 + r;
                if (node < N) out[(size_t)node * D + fcol] = acc[i][r];
            }
        }
        __syncthreads();   // protect mtile before next iteration's gather
    }
}

// ================= host launcher ============================================
extern "C" void kernel_launch(void* const* d_in, const int* in_sizes, int n_in,
                              void* d_out, int out_size, void* d_ws, size_t ws_size,
                              hipStream_t stream) {
    const float* x  = (const float*)d_in[0];
    const void*  ei = d_in[1];
    const float* Ws = (const float*)d_in[2];
    const float* bs = (const float*)d_in[3];
    const float* Wn = (const float*)d_in[4];
    const float* bn = (const float*)d_in[5];
    float* out = (float*)d_out;

    int N = in_sizes[0] / D;
    int E = in_sizes[1] / 2;

    int NBuk = (N + 255) >> 8;                 // 196 buckets
    int NCH  = (E + CPE - 1) / CPE;            // 49 chunk-pairs

    unsigned short* xb      = (unsigned short*)d_ws;                 // 6.40 MB
    unsigned*       staging = (unsigned*)(xb + (size_t)N * D);       // 6.15 MB
    unsigned*       lcnt_g  = staging + (size_t)NBuk * NCH * CELLCAP;// 76.8 KB

    int nbin  = 2 * NCH;                       // 98 bin blocks
    int ncast = NBuk;                          // 196 cast blocks
    bin_k<<<nbin + ncast, 256, 0, stream>>>(x, ei, staging, lcnt_g, xb,
                                            N, E, NBuk, NCH, nbin);

    int fblocks = (N + BKN - 1) / BKN;         // 391 blocks
    fuse3_k<<<fblocks, 512, 0, stream>>>(xb, staging, lcnt_g,
                                         Ws, bs, Wn, bn, out, N, NBuk, NCH);
}